// Round 14
// baseline (220.602 us; speedup 1.0000x reference)
//
#include <hip/hip_runtime.h>

// ---------- types ----------
typedef __attribute__((ext_vector_type(4))) float f32x4;
typedef __attribute__((ext_vector_type(8))) __bf16 bf16x8;
typedef __attribute__((ext_vector_type(4))) unsigned short u16x4;
typedef __attribute__((ext_vector_type(8))) unsigned short u16x8;

#define NB 4096      // batch
#define ND 512       // input dim
#define NH 2048      // mlp hidden
#define NO 512       // output dim

// ---------- helpers ----------
__device__ __forceinline__ unsigned short f2bf(float f) {
  unsigned int u = __float_as_uint(f);
  u += 0x7fffu + ((u >> 16) & 1u);          // RNE
  return (unsigned short)(u >> 16);
}
__device__ __forceinline__ float bf2f(unsigned short u) {
  return __uint_as_float(((unsigned int)u) << 16);
}
__device__ __forceinline__ void gload_lds16(const void* g, void* l) {
  __builtin_amdgcn_global_load_lds(
      (const __attribute__((address_space(1))) unsigned int*)g,
      (__attribute__((address_space(3))) unsigned int*)l, 16, 0, 0);
}
// K-tile-packed bf16 element index: [kt32][Mtot][32], chunk swizzled c^((row>>1)&3)
// (swizzle baked at PACK time so GEMM staging reads are fully linear).
__device__ __forceinline__ size_t paddr(int row, int k, int Mtot) {
  int kt = k >> 5, c = (k >> 3) & 3, el = k & 7;
  return ((size_t)kt * Mtot + row) * 32 + (size_t)((c ^ ((row >> 1) & 3)) * 8 + el);
}

// ---------- gating ----------
__global__ void gate_kernel(const float* __restrict__ x, const float* __restrict__ emask,
                            const float* __restrict__ gw, const float* __restrict__ gb,
                            float* __restrict__ w_out, float* __restrict__ mask_out) {
  int b = blockIdx.x;
  int lane = threadIdx.x;
  float l8[8] = {0,0,0,0,0,0,0,0};
  const float* xr = x + (size_t)b * ND;
  for (int d = lane; d < ND; d += 64) {
    float xv = xr[d];
    const float* g = gw + d * 8;
#pragma unroll
    for (int e = 0; e < 8; ++e) l8[e] = fmaf(xv, g[e], l8[e]);
  }
#pragma unroll
  for (int off = 32; off > 0; off >>= 1) {
#pragma unroll
    for (int e = 0; e < 8; ++e) l8[e] += __shfl_xor(l8[e], off);
  }
  float m = -1e30f;
#pragma unroll
  for (int e = 0; e < 8; ++e) { l8[e] += gb[e]; m = fmaxf(m, l8[e]); }
  float s = 0.f, p[8];
#pragma unroll
  for (int e = 0; e < 8; ++e) { p[e] = expf(l8[e] - m); s += p[e]; }
  float inv = 1.f / s;
  float mk[8], me[8], ms = 0.f;
#pragma unroll
  for (int e = 0; e < 8; ++e) {
    mk[e] = emask[(size_t)b * 8 + e];
    me[e] = p[e] * inv * mk[e];
    ms += me[e];
  }
  float winv = 1.f / (ms + 1e-9f);
  if (lane == 0) {
#pragma unroll
    for (int e = 0; e < 8; ++e) {
      w_out[(size_t)b * 8 + e] = me[e] * winv;
      mask_out[(size_t)b * 8 + e] = mk[e];
    }
  }
}

// ---------- cast x to bf16, packed ----------
__global__ void cast_x_kernel(const float* __restrict__ x, unsigned short* __restrict__ xb) {
  size_t t = (size_t)blockIdx.x * 256 + threadIdx.x;   // one 8-elem chunk each
  int b = (int)(t >> 6);
  int k0 = ((int)t & 63) * 8;
  const f32x4* px = (const f32x4*)(x + (size_t)b * ND + k0);
  f32x4 v0 = px[0], v1 = px[1];
  u16x8 r;
#pragma unroll
  for (int j = 0; j < 4; ++j) { r[j] = f2bf(v0[j]); r[4 + j] = f2bf(v1[j]); }
  *(u16x8*)(xb + paddr(b, k0, NB)) = r;
}

// ---------- B-spline basis, packed ----------
__global__ void basis_kernel(const float* __restrict__ x, unsigned short* __restrict__ bas) {
  size_t t = (size_t)blockIdx.x * 256 + threadIdx.x;   // = b*512 + i
  int b = (int)(t >> 9);
  int i = (int)(t & 511);
  float xv = x[t];
  const float hg = 0.4f;
  float tt[12];
#pragma unroll
  for (int j = 0; j < 12; ++j) tt[j] = -2.2f + hg * (float)j;
  float b0[11];
#pragma unroll
  for (int j = 0; j < 11; ++j) b0[j] = (tt[j] <= xv && xv < tt[j + 1]) ? 1.f : 0.f;
  float b1[10], b2[9], b3[8];
#pragma unroll
  for (int j = 0; j < 10; ++j) b1[j] = ((xv - tt[j]) * b0[j] + (tt[j + 2] - xv) * b0[j + 1]) * (1.f / (1.f * hg));
#pragma unroll
  for (int j = 0; j < 9; ++j)  b2[j] = ((xv - tt[j]) * b1[j] + (tt[j + 3] - xv) * b1[j + 1]) * (1.f / (2.f * hg));
#pragma unroll
  for (int j = 0; j < 8; ++j)  b3[j] = ((xv - tt[j]) * b2[j] + (tt[j + 4] - xv) * b2[j + 1]) * (1.f / (3.f * hg));
  u16x8 r;
#pragma unroll
  for (int j = 0; j < 8; ++j) r[j] = f2bf(b3[j]);
  *(u16x8*)(bas + paddr(b, i * 8, NB)) = r;
}

// ---------- transpose+cast: f32 [E][R][Cc] -> packed B[Cc rows][R k] ----------
__global__ void transpose_cast(const float* __restrict__ in, unsigned short* __restrict__ outp,
                               int R, int Cc) {
  __shared__ float tile[32][33];
  int e = blockIdx.z;
  int c0 = blockIdx.x * 32, r0 = blockIdx.y * 32;
  int tx = threadIdx.x & 31, ty = threadIdx.x >> 5;   // 32 x 8
  const float* ine = in + (size_t)e * R * Cc;
  unsigned short* oute = outp + (size_t)e * R * Cc;
#pragma unroll
  for (int j = 0; j < 32; j += 8)
    tile[ty + j][tx] = ine[(size_t)(r0 + ty + j) * Cc + (c0 + tx)];
  __syncthreads();
#pragma unroll
  for (int j = 0; j < 32; j += 8)
    oute[paddr(c0 + ty + j, r0 + tx, Cc)] = f2bf(tile[tx][ty + j]);
}

// ---------- ceff = coeff*scaling, packed B[512 rows][4096 k] per expert ----------
__global__ void make_cefft(const float* __restrict__ coeff, const float* __restrict__ scal,
                           unsigned short* __restrict__ outp) {
  size_t t = (size_t)blockIdx.x * 256 + threadIdx.x;  // over 4*512*512, i innermost
  int i = (int)(t & 511);
  int o = (int)((t >> 9) & 511);
  int e = (int)(t >> 18);
  size_t io = ((size_t)e * 512 + i) * 512 + o;
  const f32x4* cp = (const f32x4*)(coeff + io * 8);
  f32x4 c0 = cp[0], c1 = cp[1];
  float s = scal[io];
  u16x8 r;
#pragma unroll
  for (int j = 0; j < 4; ++j) r[j] = f2bf(c0[j] * s);
#pragma unroll
  for (int j = 0; j < 4; ++j) r[4 + j] = f2bf(c1[j] * s);
  *(u16x8*)(outp + (size_t)e * NO * (ND * 8) + paddr(o, i * 8, NO)) = r;
}

// ---------- GEMM args ----------
struct GemmArgs {
  const unsigned short* A; size_t sAe; int Ma;   // packed [kt32][Ma][32]
  const unsigned short* B; size_t sBe; int Mb;   // packed [kt32][Mb][32]
  const float* bias; int sBias;
  unsigned short* C; size_t sCe; size_t sHalf; int ldc;
  int Kspan; int zshift; int gx; int nxy;
  int mode;                                       // 0: relu+bias -> PACKED C; 2: raw -> row-major C
};

// ---------- ROUND 14: m201-style 8-phase GEMM ----------
// BM=BN=256, BK=64 (2 kt32 units), 8 waves (2M x 4N), 2 K-tiles per iteration.
// LDS 128KB: A slot s at s*32768 ([ks 16KB][ks 16KB]), B at 65536 + s*32768.
// K-tile T -> slot T&1. Iter i: ph0-3 compute T0=2i (slot0), ph4-7 T1 (slot1).
// Per phase: {4-or-8 ds_read_b128; 1 half-tile stage (2x gload_lds, 16KB
// contiguous - packed layout); barrier; lgkmcnt(0)+sched_barrier; setprio(1)
// 16 MFMA setprio(0); [vmcnt]; barrier}.
// Stage rotation (6-phase issue-to-use lead, ~5000cy >> 900cy HBM):
//   ph0: A[T1][ks1]  ph1: B[T1][ks1]  ph2: A[T0+2][ks0] ph3: B[T0+2][ks0]
//   ph4: A[T0+2][ks1] ph5: B[T0+2][ks1] ph6: A[T1+2][ks0] ph7: B[T1+2][ks0]
// WAR-safe: each staged block's last reader finished >=1 barrier before issue.
// Counted waits (2 loads/unit): vmcnt(4) end-ph1 (guarantees <= ph7(i-1):
// covers ph2-5 reads) and vmcnt(4) end-ph5 (guarantees <= ph3(i): covers
// ph6-7 + next ph0-1 reads); last iter end-ph5 -> vmcnt(0).
// Prologue: 6 units {A0k0,B0k0,A0k1,B0k1,A1k0,B1k0}, vmcnt(4) (tile0 landed).
__global__ __launch_bounds__(512, 2) void gemm_fused(int nL1, GemmArgs a1, GemmArgs a2) {
  __shared__ __align__(16) char ls[131072];
  const int wg = blockIdx.x;
  const GemmArgs g = (wg < nL1) ? a1 : a2;
  const int wgl = (wg < nL1) ? wg : wg - nL1;
  const int tid = threadIdx.x;
  const int lane = tid & 63, wid = tid >> 6;
  const int wr = wid >> 2, wc = wid & 3;           // 2M x 4N waves, 128x64 each
  const int z = wgl / g.nxy;
  int rem = wgl % g.nxy;
  rem = (rem & 7) * (g.nxy >> 3) + (rem >> 3);     // bijective %8 swizzle (nxy%8==0)
  const int bcol = (rem % g.gx) * 256;
  const int brow = (rem / g.gx) * 256;
  const int e = z >> g.zshift;
  const int half = z & ((1 << g.zshift) - 1);
  const int ktBase = half * (g.Kspan >> 5);        // in kt32 units
  const unsigned short* Ae = g.A + (size_t)e * g.sAe;
  const unsigned short* Be = g.B + (size_t)e * g.sBe;
  const int Ma = g.Ma, Mb = g.Mb;
  const int NT = g.Kspan >> 6;                     // BK=64 tiles
  const int NI = NT >> 1;

  const int fr = lane & 15, fc = lane >> 4;

  // stage one 16KB unit: matrix m, K-tile T, ks half -> slot T&1
  auto stA = [&](int S, int T, int ks) {
    const char* src = (const char*)Ae + ((size_t)(ktBase + 2 * T + ks) * Ma + brow) * 64;
    char* dst = ls + S * 32768 + ks * 16384;
    gload_lds16(src + tid * 16, dst + tid * 16);
    gload_lds16(src + 8192 + tid * 16, dst + 8192 + tid * 16);
  };
  auto stB = [&](int S, int T, int ks) {
    const char* src = (const char*)Be + ((size_t)(ktBase + 2 * T + ks) * Mb + bcol) * 64;
    char* dst = ls + 65536 + S * 32768 + ks * 16384;
    gload_lds16(src + tid * 16, dst + tid * 16);
    gload_lds16(src + 8192 + tid * 16, dst + 8192 + tid * 16);
  };

  f32x4 acc[8][4] = {};
  bf16x8 af[4], bfrag[4];

#define PH(S, KS, M, NEWB, STG, WT)                                              \
  do {                                                                           \
    if (NEWB) {                                                                  \
      _Pragma("unroll") for (int ni = 0; ni < 4; ++ni) {                         \
        int r = wc * 64 + ni * 16 + fr;                                          \
        bfrag[ni] = *(const bf16x8*)(ls + 65536 + (S) * 32768 + (KS) * 16384 +   \
                                     r * 64 + ((fc ^ ((r >> 1) & 3)) << 4));     \
      }                                                                          \
    }                                                                            \
    _Pragma("unroll") for (int mi = 0; mi < 4; ++mi) {                           \
      int r = (M) * 128 + mi * 32 + wr * 16 + fr;                                \
      af[mi] = *(const bf16x8*)(ls + (S) * 32768 + (KS) * 16384 +                \
                                r * 64 + ((fc ^ ((r >> 1) & 3)) << 4));          \
    }                                                                            \
    STG;                                                                         \
    __builtin_amdgcn_s_barrier();                                                \
    asm volatile("s_waitcnt lgkmcnt(0)" ::: "memory");                           \
    __builtin_amdgcn_sched_barrier(0);                                           \
    __builtin_amdgcn_s_setprio(1);                                               \
    _Pragma("unroll") for (int mi = 0; mi < 4; ++mi)                             \
      _Pragma("unroll") for (int ni = 0; ni < 4; ++ni)                           \
        acc[(M) * 4 + mi][ni] = __builtin_amdgcn_mfma_f32_16x16x32_bf16(         \
            bfrag[ni], af[mi], acc[(M) * 4 + mi][ni], 0, 0, 0);                  \
    __builtin_amdgcn_s_setprio(0);                                               \
    WT;                                                                          \
    __builtin_amdgcn_s_barrier();                                                \
  } while (0)

  // prologue: units u1..u6 = A0k0,B0k0,A0k1,B0k1,A1k0,B1k0; vmcnt(4) = tile0 landed
  stA(0, 0, 0); stB(0, 0, 0); stA(0, 0, 1); stB(0, 0, 1); stA(1, 1, 0); stB(1, 1, 0);
  asm volatile("s_waitcnt vmcnt(4)" ::: "memory");
  __builtin_amdgcn_s_barrier();

  for (int i = 0; i < NI; ++i) {
    const int T0 = 2 * i, T1 = 2 * i + 1;
    const bool pf = (i + 1 < NI);
    PH(0, 0, 0, true,  { stA(1, T1, 1); }, {});
    PH(0, 0, 1, false, { stB(1, T1, 1); },
       { asm volatile("s_waitcnt vmcnt(4)" ::: "memory"); });
    PH(0, 1, 0, true,  { if (pf) stA(0, T0 + 2, 0); }, {});
    PH(0, 1, 1, false, { if (pf) stB(0, T0 + 2, 0); }, {});
    PH(1, 0, 0, true,  { if (pf) stA(0, T0 + 2, 1); }, {});
    PH(1, 0, 1, false, { if (pf) stB(0, T0 + 2, 1); },
       { if (pf) asm volatile("s_waitcnt vmcnt(4)" ::: "memory");
         else    asm volatile("s_waitcnt vmcnt(0)" ::: "memory"); });
    PH(1, 1, 0, true,  { if (pf) stA(1, T1 + 2, 0); }, {});
    PH(1, 1, 1, false, { if (pf) stB(1, T1 + 2, 0); }, {});
  }
#undef PH

  // ---- epilogue: thread holds C[row][col0..col0+3] (R6-verified mapping) ----
  unsigned short* Ce = g.C + (size_t)e * g.sCe + (size_t)half * g.sHalf;
  const int ldc = g.ldc;
#pragma unroll
  for (int m = 0; m < 2; ++m)
#pragma unroll
    for (int mi = 0; mi < 4; ++mi) {
      int row = brow + m * 128 + mi * 32 + wr * 16 + fr;
#pragma unroll
      for (int ni = 0; ni < 4; ++ni) {
        int col0 = bcol + wc * 64 + ni * 16 + (fc << 2);
        u16x4 r;
        if (g.mode == 0) {
          f32x4 bv = *(const f32x4*)(g.bias + e * g.sBias + col0);
#pragma unroll
          for (int j = 0; j < 4; ++j) r[j] = f2bf(fmaxf(acc[m * 4 + mi][ni][j] + bv[j], 0.f));
          *(u16x4*)(Ce + paddr(row, col0, NB)) = r;       // packed (consumed as L2's A)
        } else {
#pragma unroll
          for (int j = 0; j < 4; ++j) r[j] = f2bf(acc[m * 4 + mi][ni][j]);
          *(u16x4*)(Ce + (size_t)row * ldc + col0) = r;   // row-major (combine input)
        }
      }
    }
}

// ---------- final weighted combine: sums split-K partials + bias ----------
__global__ void combine_kernel(const unsigned short* __restrict__ eoM,
                               const unsigned short* __restrict__ eoK,
                               const float* __restrict__ b2,
                               const float* __restrict__ w, float* __restrict__ out) {
  int b = blockIdx.x;
  int o = threadIdx.x * 4;
  float wv[8];
#pragma unroll
  for (int e = 0; e < 8; ++e) wv[e] = w[(size_t)b * 8 + e];
  f32x4 acc = {0.f, 0.f, 0.f, 0.f};
#pragma unroll
  for (int e = 0; e < 4; ++e) {
    u16x4 m0 = *(const u16x4*)(eoM + ((size_t)e * NB + b) * NO + o);
    u16x4 m1 = *(const u16x4*)(eoM + ((size_t)(4 + e) * NB + b) * NO + o);
    f32x4 bb = *(const f32x4*)(b2 + e * NO + o);
#pragma unroll
    for (int j = 0; j < 4; ++j)
      acc[j] = fmaf(wv[e], bf2f(m0[j]) + bf2f(m1[j]) + bb[j], acc[j]);
  }
#pragma unroll
  for (int e = 0; e < 4; ++e) {
    u16x4 k0 = *(const u16x4*)(eoK + ((size_t)e * NB + b) * NO + o);
    u16x4 k1 = *(const u16x4*)(eoK + ((size_t)(4 + e) * NB + b) * NO + o);
#pragma unroll
    for (int j = 0; j < 4; ++j)
      acc[j] = fmaf(wv[4 + e], bf2f(k0[j]) + bf2f(k1[j]), acc[j]);
  }
  *(f32x4*)(out + (size_t)b * NO + o) = acc;
}

// ---------- launch ----------
extern "C" void kernel_launch(void* const* d_in, const int* in_sizes, int n_in,
                              void* d_out, int out_size, void* d_ws, size_t ws_size,
                              hipStream_t stream) {
  (void)in_sizes; (void)n_in; (void)out_size;
  const float* x      = (const float*)d_in[0];
  const float* emask  = (const float*)d_in[1];
  const float* gate_w = (const float*)d_in[2];
  const float* gate_b = (const float*)d_in[3];
  const float* mlp_w1 = (const float*)d_in[4];
  const float* mlp_b1 = (const float*)d_in[5];
  const float* mlp_w2 = (const float*)d_in[6];
  const float* mlp_b2 = (const float*)d_in[7];
  const float* kan_s  = (const float*)d_in[8];
  const float* kan_c  = (const float*)d_in[9];

  float* out = (float*)d_out;
  float* mask_out = out + (size_t)NB * NO;
  float* w_out    = mask_out + (size_t)NB * 8;

  char* ws = (char*)d_ws;
  size_t off = 0;
  auto take = [&](size_t bytes) { size_t r = off; off += (bytes + 255) & ~(size_t)255; return r; };
  unsigned short* w1t   = (unsigned short*)(ws + take((size_t)4 * NH * ND * 2));       // 8.39 MB
  unsigned short* w2t   = (unsigned short*)(ws + take((size_t)4 * NO * NH * 2));       // 8.39 MB
  unsigned short* cefft = (unsigned short*)(ws + take((size_t)4 * NO * (ND * 8) * 2)); // 16.78 MB
  unsigned short* xbf   = (unsigned short*)(ws + take((size_t)NB * ND * 2));           // 4.19 MB
  unsigned short* regA  = (unsigned short*)(ws + take((size_t)8 * NB * NO * 2));       // 33.55 MB
  unsigned short* hbuf  = (unsigned short*)(ws + take((size_t)4 * NB * NH * 2));       // 67.11 MB
  size_t base_need = off;                                                              // ~138.4 MB
  size_t eoK_off = base_need;
  const bool fused = (ws_size >= base_need + (size_t)8 * NB * NO * 2);
  unsigned short* eoM = regA;
  unsigned short* bas, *eoK;
  if (fused) {
    bas = regA;                                              // basis lives in regA pre-L2
    eoK = (unsigned short*)(ws + eoK_off);                   // 33.55 MB tail
  } else {
    bas = hbuf;                                              // fallback aliases
    eoK = (unsigned short*)((char*)hbuf + (size_t)2 * NB * NH * 2);
  }

  gate_kernel<<<NB, 64, 0, stream>>>(x, emask, gate_w, gate_b, w_out, mask_out);
  cast_x_kernel<<<(NB * ND / 8) / 256, 256, 0, stream>>>(x, xbf);
  transpose_cast<<<dim3(NH / 32, ND / 32, 4), 256, 0, stream>>>(mlp_w1, w1t, ND, NH);
  transpose_cast<<<dim3(NO / 32, NH / 32, 4), 256, 0, stream>>>(mlp_w2, w2t, NH, NO);
  make_cefft<<<(4 * ND * NO) / 256, 256, 0, stream>>>(kan_c, kan_s, cefft);

  GemmArgs aL1 = { xbf, 0, NB,
                   w1t, (size_t)NH * ND, NH,
                   mlp_b1, NH,
                   hbuf, (size_t)NB * NH, 0, NH,
                   ND, 0, NH / 256, (NH / 256) * (NB / 256), 0 };
  GemmArgs aL2 = { hbuf, (size_t)NB * NH, NB,
                   w2t, (size_t)NO * NH, NO,
                   nullptr, 0,
                   eoM, (size_t)NB * NO, (size_t)4 * NB * NO, NO,
                   NH / 2, 1, NO / 256, (NO / 256) * (NB / 256), 2 };
  GemmArgs aL3 = { bas, 0, NB,
                   cefft, (size_t)NO * (ND * 8), NO,
                   nullptr, 0,
                   eoK, (size_t)NB * NO, (size_t)4 * NB * NO, NO,
                   (ND * 8) / 2, 1, NO / 256, (NO / 256) * (NB / 256), 2 };

  if (fused) {
    basis_kernel<<<(NB * ND) / 256, 256, 0, stream>>>(x, bas);
    gemm_fused<<<512 + 256, 512, 0, stream>>>(512, aL1, aL3);
    gemm_fused<<<256, 512, 0, stream>>>(0, aL2, aL2);
  } else {
    gemm_fused<<<512, 512, 0, stream>>>(512, aL1, aL1);
    gemm_fused<<<256, 512, 0, stream>>>(0, aL2, aL2);
    basis_kernel<<<(NB * ND) / 256, 256, 0, stream>>>(x, bas);
    gemm_fused<<<256, 512, 0, stream>>>(0, aL3, aL3);
  }

  combine_kernel<<<NB, NO / 4, 0, stream>>>(eoM, eoK, mlp_b2, w_out, out);
}

// Round 15
// 213.127 us; speedup vs baseline: 1.0351x; 1.0351x over previous
//
#include <hip/hip_runtime.h>

// ---------- types ----------
typedef __attribute__((ext_vector_type(4))) float f32x4;
typedef __attribute__((ext_vector_type(8))) __bf16 bf16x8;
typedef __attribute__((ext_vector_type(4))) unsigned short u16x4;
typedef __attribute__((ext_vector_type(8))) unsigned short u16x8;

#define NB 4096      // batch
#define ND 512       // input dim
#define NH 2048      // mlp hidden
#define NO 512       // output dim

// ---------- helpers ----------
__device__ __forceinline__ unsigned short f2bf(float f) {
  unsigned int u = __float_as_uint(f);
  u += 0x7fffu + ((u >> 16) & 1u);          // RNE
  return (unsigned short)(u >> 16);
}
__device__ __forceinline__ float bf2f(unsigned short u) {
  return __uint_as_float(((unsigned int)u) << 16);
}
__device__ __forceinline__ void gload_lds16(const void* g, void* l) {
  __builtin_amdgcn_global_load_lds(
      (const __attribute__((address_space(1))) unsigned int*)g,
      (__attribute__((address_space(3))) unsigned int*)l, 16, 0, 0);
}
// K-tile-packed bf16 element index: [kt32][Mtot][32], chunk swizzled c^((row>>1)&3)
// (swizzle baked at PACK time so GEMM staging reads are fully linear).
__device__ __forceinline__ size_t paddr(int row, int k, int Mtot) {
  int kt = k >> 5, c = (k >> 3) & 3, el = k & 7;
  return ((size_t)kt * Mtot + row) * 32 + (size_t)((c ^ ((row >> 1) & 3)) * 8 + el);
}

// ---------- gating ----------
__global__ void gate_kernel(const float* __restrict__ x, const float* __restrict__ emask,
                            const float* __restrict__ gw, const float* __restrict__ gb,
                            float* __restrict__ w_out, float* __restrict__ mask_out) {
  int b = blockIdx.x;
  int lane = threadIdx.x;
  float l8[8] = {0,0,0,0,0,0,0,0};
  const float* xr = x + (size_t)b * ND;
  for (int d = lane; d < ND; d += 64) {
    float xv = xr[d];
    const float* g = gw + d * 8;
#pragma unroll
    for (int e = 0; e < 8; ++e) l8[e] = fmaf(xv, g[e], l8[e]);
  }
#pragma unroll
  for (int off = 32; off > 0; off >>= 1) {
#pragma unroll
    for (int e = 0; e < 8; ++e) l8[e] += __shfl_xor(l8[e], off);
  }
  float m = -1e30f;
#pragma unroll
  for (int e = 0; e < 8; ++e) { l8[e] += gb[e]; m = fmaxf(m, l8[e]); }
  float s = 0.f, p[8];
#pragma unroll
  for (int e = 0; e < 8; ++e) { p[e] = expf(l8[e] - m); s += p[e]; }
  float inv = 1.f / s;
  float mk[8], me[8], ms = 0.f;
#pragma unroll
  for (int e = 0; e < 8; ++e) {
    mk[e] = emask[(size_t)b * 8 + e];
    me[e] = p[e] * inv * mk[e];
    ms += me[e];
  }
  float winv = 1.f / (ms + 1e-9f);
  if (lane == 0) {
#pragma unroll
    for (int e = 0; e < 8; ++e) {
      w_out[(size_t)b * 8 + e] = me[e] * winv;
      mask_out[(size_t)b * 8 + e] = mk[e];
    }
  }
}

// ---------- cast x to bf16, packed ----------
__global__ void cast_x_kernel(const float* __restrict__ x, unsigned short* __restrict__ xb) {
  size_t t = (size_t)blockIdx.x * 256 + threadIdx.x;   // one 8-elem chunk each
  int b = (int)(t >> 6);
  int k0 = ((int)t & 63) * 8;
  const f32x4* px = (const f32x4*)(x + (size_t)b * ND + k0);
  f32x4 v0 = px[0], v1 = px[1];
  u16x8 r;
#pragma unroll
  for (int j = 0; j < 4; ++j) { r[j] = f2bf(v0[j]); r[4 + j] = f2bf(v1[j]); }
  *(u16x8*)(xb + paddr(b, k0, NB)) = r;
}

// ---------- B-spline basis, packed ----------
__global__ void basis_kernel(const float* __restrict__ x, unsigned short* __restrict__ bas) {
  size_t t = (size_t)blockIdx.x * 256 + threadIdx.x;   // = b*512 + i
  int b = (int)(t >> 9);
  int i = (int)(t & 511);
  float xv = x[t];
  const float hg = 0.4f;
  float tt[12];
#pragma unroll
  for (int j = 0; j < 12; ++j) tt[j] = -2.2f + hg * (float)j;
  float b0[11];
#pragma unroll
  for (int j = 0; j < 11; ++j) b0[j] = (tt[j] <= xv && xv < tt[j + 1]) ? 1.f : 0.f;
  float b1[10], b2[9], b3[8];
#pragma unroll
  for (int j = 0; j < 10; ++j) b1[j] = ((xv - tt[j]) * b0[j] + (tt[j + 2] - xv) * b0[j + 1]) * (1.f / (1.f * hg));
#pragma unroll
  for (int j = 0; j < 9; ++j)  b2[j] = ((xv - tt[j]) * b1[j] + (tt[j + 3] - xv) * b1[j + 1]) * (1.f / (2.f * hg));
#pragma unroll
  for (int j = 0; j < 8; ++j)  b3[j] = ((xv - tt[j]) * b2[j] + (tt[j + 4] - xv) * b2[j + 1]) * (1.f / (3.f * hg));
  u16x8 r;
#pragma unroll
  for (int j = 0; j < 8; ++j) r[j] = f2bf(b3[j]);
  *(u16x8*)(bas + paddr(b, i * 8, NB)) = r;
}

// ---------- transpose+cast: f32 [E][R][Cc] -> packed B[Cc rows][R k] ----------
__global__ void transpose_cast(const float* __restrict__ in, unsigned short* __restrict__ outp,
                               int R, int Cc) {
  __shared__ float tile[32][33];
  int e = blockIdx.z;
  int c0 = blockIdx.x * 32, r0 = blockIdx.y * 32;
  int tx = threadIdx.x & 31, ty = threadIdx.x >> 5;   // 32 x 8
  const float* ine = in + (size_t)e * R * Cc;
  unsigned short* oute = outp + (size_t)e * R * Cc;
#pragma unroll
  for (int j = 0; j < 32; j += 8)
    tile[ty + j][tx] = ine[(size_t)(r0 + ty + j) * Cc + (c0 + tx)];
  __syncthreads();
#pragma unroll
  for (int j = 0; j < 32; j += 8)
    oute[paddr(c0 + ty + j, r0 + tx, Cc)] = f2bf(tile[tx][ty + j]);
}

// ---------- ceff = coeff*scaling, packed B[512 rows][4096 k] per expert ----------
__global__ void make_cefft(const float* __restrict__ coeff, const float* __restrict__ scal,
                           unsigned short* __restrict__ outp) {
  size_t t = (size_t)blockIdx.x * 256 + threadIdx.x;  // over 4*512*512, i innermost
  int i = (int)(t & 511);
  int o = (int)((t >> 9) & 511);
  int e = (int)(t >> 18);
  size_t io = ((size_t)e * 512 + i) * 512 + o;
  const f32x4* cp = (const f32x4*)(coeff + io * 8);
  f32x4 c0 = cp[0], c1 = cp[1];
  float s = scal[io];
  u16x8 r;
#pragma unroll
  for (int j = 0; j < 4; ++j) r[j] = f2bf(c0[j] * s);
#pragma unroll
  for (int j = 0; j < 4; ++j) r[4 + j] = f2bf(c1[j] * s);
  *(u16x8*)(outp + (size_t)e * NO * (ND * 8) + paddr(o, i * 8, NO)) = r;
}

// ---------- GEMM args (runtime role selection) ----------
struct GemmArgs {
  const unsigned short* A; size_t sAe; int Ma;   // packed [kt32][Ma][32]
  const unsigned short* B; size_t sBe; int Mb;   // packed [kt32][Mb][32]
  const float* bias; int sBias;
  unsigned short* C; size_t sCe; size_t sHalf; int ldc;
  int Kspan; int zshift; int gx; int nxy;
  int mode;                                       // 0: relu+bias -> PACKED C; 2: raw -> row-major C
};

// ---------- GEMM: C[M,N] = A[M,K]*B[N,K]^T, bf16 in/out ----------
// ROUND 15: occupancy-x-tile sweet spot. R12-R14 all ran 1 WG/CU (96-128KB
// LDS) and showed MfmaUtil 35% + VALUBusy 20% -> ~45% of cycles idle: the
// single resident WG's barrier/vmcnt stalls have nothing to hide behind.
// New geometry: BM=128, BN=256, BK=32, 8 waves (2M x 4N), per-wave 64x64.
// LDS ring-3 x 24KB (A 8KB + B 16KB) = 72KB -> 2 WGs/CU (16 waves, 4/SIMD;
// acc[4][4] ~72 VGPR fits). Co-resident WGs fill each other's stalls (m114).
// Everything else is R13-proven: packed operands (staging = 3 fully-linear
// 8KB gloads), NO mid-tile barrier (waves drift; compiler emits fine-grained
// lgkmcnt for read->MFMA deps), stage-after-reads, counted vmcnt(3) at tile
// end (3 loads/tile, distance-2 ring-3; same WAR argument that passed R13).
__global__ __launch_bounds__(512, 2) void gemm_fused(int nL1, GemmArgs a1, GemmArgs a2) {
  __shared__ __align__(16) char ls[3 * 24576];
  const int wg = blockIdx.x;
  const GemmArgs g = (wg < nL1) ? a1 : a2;
  const int wgl = (wg < nL1) ? wg : wg - nL1;
  const int tid = threadIdx.x;
  const int lane = tid & 63, wid = tid >> 6;
  const int wr = wid >> 2, wc = wid & 3;           // 2M x 4N waves, 64x64 each
  const int z = wgl / g.nxy;
  int rem = wgl % g.nxy;
  rem = (rem & 7) * (g.nxy >> 3) + (rem >> 3);     // bijective %8 swizzle (nxy%8==0)
  const int bcol = (rem % g.gx) * 256;
  const int brow = (rem / g.gx) * 128;
  const int e = z >> g.zshift;
  const int half = z & ((1 << g.zshift) - 1);
  const int ktBase = half * (g.Kspan >> 5);        // kt32 units
  const unsigned short* Ae = g.A + (size_t)e * g.sAe;
  const unsigned short* Be = g.B + (size_t)e * g.sBe;
  const int Ma = g.Ma, Mb = g.Mb;
  const int NT = g.Kspan >> 5;

  const int fr = lane & 15, fc = lane >> 4;

  auto stage = [&](int buf, int t2) {
    const char* sa = (const char*)Ae + ((size_t)(ktBase + t2) * Ma + brow) * 64;
    gload_lds16(sa + tid * 16, ls + buf * 24576 + tid * 16);
    const char* sb = (const char*)Be + ((size_t)(ktBase + t2) * Mb + bcol) * 64;
    gload_lds16(sb + tid * 16, ls + buf * 24576 + 8192 + tid * 16);
    gload_lds16(sb + 8192 + tid * 16, ls + buf * 24576 + 16384 + tid * 16);
  };

  f32x4 acc[4][4] = {};

  // prologue: stage tiles 0,1 (6 loads); wait tile0 only (tile1's 3 in flight)
  stage(0, 0);
  stage(1, 1);
  asm volatile("s_waitcnt vmcnt(3)" ::: "memory");
  __builtin_amdgcn_s_barrier();

  int bi = 0;
  for (int t = 0; t < NT; ++t) {
    const char* bA = ls + bi * 24576;
    const char* bB = bA + 8192;
    const int pb = (bi == 0) ? 2 : bi - 1;       // == (t+2) % 3
    const bool pf = (t + 2 < NT);

    bf16x8 af[4], bfrag[4];
#pragma unroll
    for (int i = 0; i < 4; ++i) {
      int ra = wr * 64 + i * 16 + fr;
      af[i] = *(const bf16x8*)(bA + ra * 64 + ((fc ^ ((ra >> 1) & 3)) << 4));
    }
#pragma unroll
    for (int n = 0; n < 4; ++n) {
      int rb = wc * 64 + n * 16 + fr;
      bfrag[n] = *(const bf16x8*)(bB + rb * 64 + ((fc ^ ((rb >> 1) & 3)) << 4));
    }
    if (pf) stage(pb, t + 2);
    // no mid-tile barrier / lgkmcnt(0) / sched_barrier: waves drift, the 2nd
    // resident WG + drifted waves fill the LDS/MFMA pipes during stalls.
#pragma unroll
    for (int mi = 0; mi < 4; ++mi)
#pragma unroll
      for (int ni = 0; ni < 4; ++ni)
        acc[mi][ni] = __builtin_amdgcn_mfma_f32_16x16x32_bf16(bfrag[ni], af[mi], acc[mi][ni], 0, 0, 0);
    if (pf)               asm volatile("s_waitcnt vmcnt(3)" ::: "memory");  // t+1 landed
    else if (t + 1 < NT)  asm volatile("s_waitcnt vmcnt(0)" ::: "memory");
    __builtin_amdgcn_s_barrier();

    bi = (bi == 2) ? 0 : bi + 1;
  }

  // ---- epilogue: thread holds C[row][col0..col0+3] ----
  unsigned short* Ce = g.C + (size_t)e * g.sCe + (size_t)half * g.sHalf;
  const int ldc = g.ldc;
#pragma unroll
  for (int mi = 0; mi < 4; ++mi) {
    int row = brow + wr * 64 + mi * 16 + fr;
#pragma unroll
    for (int ni = 0; ni < 4; ++ni) {
      int col0 = bcol + wc * 64 + ni * 16 + (fc << 2);
      u16x4 r;
      if (g.mode == 0) {
        f32x4 bv = *(const f32x4*)(g.bias + e * g.sBias + col0);
#pragma unroll
        for (int j = 0; j < 4; ++j) r[j] = f2bf(fmaxf(acc[mi][ni][j] + bv[j], 0.f));
        *(u16x4*)(Ce + paddr(row, col0, NB)) = r;       // packed (consumed as L2's A)
      } else {
#pragma unroll
        for (int j = 0; j < 4; ++j) r[j] = f2bf(acc[mi][ni][j]);
        *(u16x4*)(Ce + (size_t)row * ldc + col0) = r;   // row-major (combine input)
      }
    }
  }
}

// ---------- final weighted combine: sums split-K partials + bias ----------
__global__ void combine_kernel(const unsigned short* __restrict__ eoM,
                               const unsigned short* __restrict__ eoK,
                               const float* __restrict__ b2,
                               const float* __restrict__ w, float* __restrict__ out) {
  int b = blockIdx.x;
  int o = threadIdx.x * 4;
  float wv[8];
#pragma unroll
  for (int e = 0; e < 8; ++e) wv[e] = w[(size_t)b * 8 + e];
  f32x4 acc = {0.f, 0.f, 0.f, 0.f};
#pragma unroll
  for (int e = 0; e < 4; ++e) {
    u16x4 m0 = *(const u16x4*)(eoM + ((size_t)e * NB + b) * NO + o);
    u16x4 m1 = *(const u16x4*)(eoM + ((size_t)(4 + e) * NB + b) * NO + o);
    f32x4 bb = *(const f32x4*)(b2 + e * NO + o);
#pragma unroll
    for (int j = 0; j < 4; ++j)
      acc[j] = fmaf(wv[e], bf2f(m0[j]) + bf2f(m1[j]) + bb[j], acc[j]);
  }
#pragma unroll
  for (int e = 0; e < 4; ++e) {
    u16x4 k0 = *(const u16x4*)(eoK + ((size_t)e * NB + b) * NO + o);
    u16x4 k1 = *(const u16x4*)(eoK + ((size_t)(4 + e) * NB + b) * NO + o);
#pragma unroll
    for (int j = 0; j < 4; ++j)
      acc[j] = fmaf(wv[4 + e], bf2f(k0[j]) + bf2f(k1[j]), acc[j]);
  }
  *(f32x4*)(out + (size_t)b * NO + o) = acc;
}

// ---------- launch ----------
extern "C" void kernel_launch(void* const* d_in, const int* in_sizes, int n_in,
                              void* d_out, int out_size, void* d_ws, size_t ws_size,
                              hipStream_t stream) {
  (void)in_sizes; (void)n_in; (void)out_size;
  const float* x      = (const float*)d_in[0];
  const float* emask  = (const float*)d_in[1];
  const float* gate_w = (const float*)d_in[2];
  const float* gate_b = (const float*)d_in[3];
  const float* mlp_w1 = (const float*)d_in[4];
  const float* mlp_b1 = (const float*)d_in[5];
  const float* mlp_w2 = (const float*)d_in[6];
  const float* mlp_b2 = (const float*)d_in[7];
  const float* kan_s  = (const float*)d_in[8];
  const float* kan_c  = (const float*)d_in[9];

  float* out = (float*)d_out;
  float* mask_out = out + (size_t)NB * NO;
  float* w_out    = mask_out + (size_t)NB * 8;

  char* ws = (char*)d_ws;
  size_t off = 0;
  auto take = [&](size_t bytes) { size_t r = off; off += (bytes + 255) & ~(size_t)255; return r; };
  unsigned short* w1t   = (unsigned short*)(ws + take((size_t)4 * NH * ND * 2));       // 8.39 MB
  unsigned short* w2t   = (unsigned short*)(ws + take((size_t)4 * NO * NH * 2));       // 8.39 MB
  unsigned short* cefft = (unsigned short*)(ws + take((size_t)4 * NO * (ND * 8) * 2)); // 16.78 MB
  unsigned short* xbf   = (unsigned short*)(ws + take((size_t)NB * ND * 2));           // 4.19 MB
  unsigned short* regA  = (unsigned short*)(ws + take((size_t)8 * NB * NO * 2));       // 33.55 MB
  unsigned short* hbuf  = (unsigned short*)(ws + take((size_t)4 * NB * NH * 2));       // 67.11 MB
  size_t base_need = off;                                                              // ~138.4 MB
  size_t eoK_off = base_need;
  const bool fused = (ws_size >= base_need + (size_t)8 * NB * NO * 2);
  unsigned short* eoM = regA;
  unsigned short* bas, *eoK;
  if (fused) {
    bas = regA;                                              // basis lives in regA pre-L2
    eoK = (unsigned short*)(ws + eoK_off);                   // 33.55 MB tail
  } else {
    bas = hbuf;                                              // fallback aliases
    eoK = (unsigned short*)((char*)hbuf + (size_t)2 * NB * NH * 2);
  }

  gate_kernel<<<NB, 64, 0, stream>>>(x, emask, gate_w, gate_b, w_out, mask_out);
  cast_x_kernel<<<(NB * ND / 8) / 256, 256, 0, stream>>>(x, xbf);
  transpose_cast<<<dim3(NH / 32, ND / 32, 4), 256, 0, stream>>>(mlp_w1, w1t, ND, NH);
  transpose_cast<<<dim3(NO / 32, NH / 32, 4), 256, 0, stream>>>(mlp_w2, w2t, NH, NO);
  make_cefft<<<(4 * ND * NO) / 256, 256, 0, stream>>>(kan_c, kan_s, cefft);

  // per-z grids: BM=128 rows, BN=256 cols
  GemmArgs aL1 = { xbf, 0, NB,
                   w1t, (size_t)NH * ND, NH,
                   mlp_b1, NH,
                   hbuf, (size_t)NB * NH, 0, NH,
                   ND, 0, NH / 256, (NH / 256) * (NB / 128), 0 };   // nxy = 8*32 = 256
  GemmArgs aL2 = { hbuf, (size_t)NB * NH, NB,
                   w2t, (size_t)NO * NH, NO,
                   nullptr, 0,
                   eoM, (size_t)NB * NO, (size_t)4 * NB * NO, NO,
                   NH / 2, 1, NO / 256, (NO / 256) * (NB / 128), 2 }; // nxy = 2*32 = 64
  GemmArgs aL3 = { bas, 0, NB,
                   cefft, (size_t)NO * (ND * 8), NO,
                   nullptr, 0,
                   eoK, (size_t)NB * NO, (size_t)4 * NB * NO, NO,
                   (ND * 8) / 2, 1, NO / 256, (NO / 256) * (NB / 128), 2 }; // nxy = 64

  const int nL1 = 4 * ((NH / 256) * (NB / 128));    // 1024
  const int nL2 = 8 * ((NO / 256) * (NB / 128));    // 512
  const int nL3 = 8 * ((NO / 256) * (NB / 128));    // 512

  if (fused) {
    basis_kernel<<<(NB * ND) / 256, 256, 0, stream>>>(x, bas);
    gemm_fused<<<nL1 + nL3, 512, 0, stream>>>(nL1, aL1, aL3);
    gemm_fused<<<nL2, 512, 0, stream>>>(0, aL2, aL2);
  } else {
    gemm_fused<<<nL1, 512, 0, stream>>>(nL1, aL1, aL1);
    gemm_fused<<<nL2, 512, 0, stream>>>(0, aL2, aL2);
    basis_kernel<<<(NB * ND) / 256, 256, 0, stream>>>(x, bas);
    gemm_fused<<<nL3, 512, 0, stream>>>(0, aL3, aL3);
  }

  combine_kernel<<<NB, NO / 4, 0, stream>>>(eoM, eoK, mlp_b2, w_out, out);
}